// Round 8
// baseline (647.356 us; speedup 1.0000x reference)
//
#include <hip/hip_runtime.h>

#define DIMV 768
#define BATCH 16
#define SEQ 1024
#define LN_EPS 1e-5f

typedef __attribute__((ext_vector_type(8))) short bf16x8;   // 8 bf16 = 4 VGPRs
typedef __attribute__((ext_vector_type(4))) float f32x4;
typedef unsigned short ushort_t;

__device__ __forceinline__ unsigned short f2bf(float f) {
    unsigned u = __float_as_uint(f);
    u = (u + 0x7FFFu + ((u >> 16) & 1u)) >> 16;
    return (unsigned short)u;
}

// ---------------------------------------------------------------------------
// Verified building blocks (rounds 0-7):
//  - LDS chunk swizzle on global SOURCE + frag-read XOR (conflicts -> 0).
//  - XCD swizzles: Z>1 -> XCD == batch (mod 8); Z==1 -> chunked y-range.
//  - Branch-fused attention; lifetime overlays -> single chunk Cb=16.
// Pipeline-depth history (all pre-committed A/B outcomes):
//  - 128^2 ring-4 depth-2: REFUTED (r4, occupancy 3->2).
//  - 256^2 ring-3 depth-1: +6.6% only (r6).
//  - 256^2 ring-4 depth-2 at ISO-occupancy: NULL (r7) -> not load latency.
// Remaining model: fixed cost per barrier period; only lever left in the
// 2-phase family = amortization -> BK=64 (12 periods instead of 24, same
// barrier count, 2x MFMA per period).
// ---------------------------------------------------------------------------

// ---------------------------------------------------------------------------
// 256x256 tile GEMM, BK=64, ring-2 double-buffer (128 KB), depth-1 counted
// prefetch, TWO barriers per iter:
//   iter k: issue(k+1 -> slot (k+1)&1); vmcnt(8); barrier_a;
//           [kh=0,1: 12 ds_read_b128 frags; 32 MFMA]; barrier_b
// Safety:
//  - barrier_a: every wave waited its OWN vmcnt(8) (its share of tile k)
//    before barrier_a -> after barrier_a all tile-k staging is complete.
//  - barrier_b: all waves' ds_reads of slot k&1 are consumed (lgkm before
//    MFMA) before barrier_b; iter k+1's issue targets slot (k+2)&1 = k&1,
//    and it executes after barrier_b(k) -> no overwrite race.
//  - last iter issues a clamped dummy (last tile, L2-hot, slot NK&1 whose
//    readers finished at iter NK-2) so the vmcnt count stays uniform.
// LDS swizzle for 128-byte rows: global chunk c = q ^ (r&7) stored at slot q;
// frag read of global chunk g uses slot g ^ (r&7): 16 lanes -> 8 bank-quads,
// 2 lanes each (2-way = free).
// mode: 0 = f32 out; 1 = bf16 out;
//       4 = fused KV epilogue, branch-stacked attention operands:
//           bh = m>>10, half = bh>=CbArg, b = bh - half*CbArg
//           n < 768 : K  -> Cout [b][half*1024 + s][n]       (bf16)
//           n >= 768: V^T-> Cout2[b][n-768][half*1024 + s]   (bf16)
// ---------------------------------------------------------------------------
__global__ __launch_bounds__(512, 2) void gemm_bf16_nt_256(
    const ushort_t* __restrict__ A, const ushort_t* __restrict__ B,
    const float* __restrict__ bias, const float* __restrict__ bias2,
    void* __restrict__ Cout, void* __restrict__ Cout2,
    int K, int lda, int ldb, int ldc, float scale, int mode,
    long long sAz, long long sBz, long long sCz, int CbArg)
{
    int bx = blockIdx.x, by = blockIdx.y, bz = blockIdx.z;
    {
        const unsigned Z  = gridDim.z;
        const unsigned nx = gridDim.x, ny = gridDim.y;
        if (Z > 1) {
            const unsigned nxy = nx * ny;
            const unsigned lid = ((unsigned)bz * ny + (unsigned)by) * nx + (unsigned)bx;
            unsigned r;
            if ((Z & 7u) == 0u) {
                const unsigned c  = lid & 7u;
                const unsigned rp = lid >> 3;
                bz = (int)(c + 8u * (rp / nxy));
                r  = rp % nxy;
            } else {
                bz = (int)(lid % Z);
                r  = lid / Z;
            }
            bx = (int)(r % nx);
            by = (int)(r / nx);
        } else {
            const unsigned nwg = nx * ny;
            if ((nwg & 7u) == 0u) {
                const unsigned lid = (unsigned)by * nx + (unsigned)bx;
                const unsigned nl  = (lid & 7u) * (nwg >> 3) + (lid >> 3);
                bx = (int)(nl % nx);
                by = (int)(nl / nx);
            }
        }
    }

    A += (long long)bz * sAz;
    B += (long long)bz * sBz;
    float*    Cf  = (float*)Cout    + ((mode == 0) ? (long long)bz * sCz : 0);
    ushort_t* Ch  = (ushort_t*)Cout + ((mode == 1) ? (long long)bz * sCz : 0);
    ushort_t* Ch2 = (ushort_t*)Cout2;

    __shared__ ushort_t As[2][256 * 64];   // 2 x 32 KB
    __shared__ ushort_t Bs[2][256 * 64];   // 2 x 32 KB  (128 KB total)

    const int t    = threadIdx.x;       // 0..511
    const int wave = t >> 6;            // 0..7
    const int lane = t & 63;
    const int quad = lane >> 4;         // 0..3
    const int lr   = lane & 15;         // 0..15
    const int wy   = wave >> 2;         // 0/1: m-half (128 rows)
    const int wx   = wave & 3;          // 0..3: n-quarter (64 cols)

    const int m0 = by * 256;
    const int n0 = bx * 256;

    const ushort_t* Abase = A + (long long)m0 * lda;
    const ushort_t* Bbase = B + (long long)n0 * ldb;

    auto issue = [&](int k0, int slot) {
        #pragma unroll
        for (int i = 0; i < 4; ++i) {
            const int idx = t + 512 * i;          // 0..2047: 256 rows x 8 chunks
            const int r   = idx >> 3;
            const int q   = idx & 7;              // LDS chunk slot
            const int c   = (q ^ (r & 7)) * 8;    // swizzled global chunk (elems)
            __builtin_amdgcn_global_load_lds(
                (const __attribute__((address_space(1))) unsigned int*)(Abase + (long long)r * lda + k0 + c),
                (__attribute__((address_space(3))) unsigned int*)&As[slot][idx * 8], 16, 0, 0);
            __builtin_amdgcn_global_load_lds(
                (const __attribute__((address_space(1))) unsigned int*)(Bbase + (long long)r * ldb + k0 + c),
                (__attribute__((address_space(3))) unsigned int*)&Bs[slot][idx * 8], 16, 0, 0);
        }
    };

    // Frag-read offsets (loop-invariant): global chunk g of row r lives at
    // LDS slot g ^ (r&7). Sub-step kh reads global chunk quad + kh*4.
    int offA[2][8], offB[2][4];
    #pragma unroll
    for (int kh = 0; kh < 2; ++kh) {
        #pragma unroll
        for (int i = 0; i < 8; ++i) {
            const int r = wy * 128 + i * 16 + lr;
            offA[kh][i] = r * 64 + (((quad + kh * 4) ^ (r & 7)) * 8);
        }
        #pragma unroll
        for (int j = 0; j < 4; ++j) {
            const int r = wx * 64 + j * 16 + lr;
            offB[kh][j] = r * 64 + (((quad + kh * 4) ^ (r & 7)) * 8);
        }
    }

    f32x4 acc[8][4] = {};

    const int NK = K >> 6;                 // BK=64; all 256^2 callers K=768 -> 12
    issue(0, 0);
    for (int ki = 0; ki < NK; ++ki) {
        const int kn = (ki + 1 < NK) ? (ki + 1) << 6 : (NK - 1) << 6;  // clamped dummy
        issue(kn, (ki + 1) & 1);
        asm volatile("s_waitcnt vmcnt(8)" ::: "memory");   // tile-k staged; k+1 in flight
        asm volatile("s_barrier" ::: "memory");            // barrier_a

        const ushort_t* as = &As[ki & 1][0];
        const ushort_t* bs = &Bs[ki & 1][0];
        #pragma unroll
        for (int kh = 0; kh < 2; ++kh) {
            bf16x8 af[8], bfr[4];
            #pragma unroll
            for (int i = 0; i < 8; ++i) af[i]  = *(const bf16x8*)&as[offA[kh][i]];
            #pragma unroll
            for (int j = 0; j < 4; ++j) bfr[j] = *(const bf16x8*)&bs[offB[kh][j]];

            __builtin_amdgcn_s_setprio(1);
            #pragma unroll
            for (int i = 0; i < 8; ++i)
                #pragma unroll
                for (int j = 0; j < 4; ++j)
                    acc[i][j] = __builtin_amdgcn_mfma_f32_16x16x32_bf16(
                        af[i], bfr[j], acc[i][j], 0, 0, 0);
            __builtin_amdgcn_s_setprio(0);
        }
        asm volatile("s_barrier" ::: "memory");            // barrier_b: reads done
    }

    // epilogue: D row(m) = quad*4 + reg, col(n) = lane&15  [m89-verified]
    #pragma unroll
    for (int j = 0; j < 4; ++j) {
        const int n = n0 + wx * 64 + j * 16 + lr;
        float bv;
        if (mode == 4) bv = (n < DIMV) ? bias[n] : bias2[n - DIMV];
        else           bv = bias ? bias[n] : 0.0f;
        #pragma unroll
        for (int i = 0; i < 8; ++i) {
            #pragma unroll
            for (int r = 0; r < 4; ++r) {
                const int m = m0 + wy * 128 + i * 16 + quad * 4 + r;
                const float val = acc[i][j][r] * scale + bv;
                if (mode == 0) {
                    Cf[(long long)m * ldc + n] = val;
                } else if (mode == 1) {
                    Ch[(long long)m * ldc + n] = f2bf(val);
                } else {                      // mode 4: fused KV, branch-stacked
                    const int bh = m >> 10, s = m & 1023;
                    const int hf = (bh >= CbArg) ? 1 : 0;
                    const int b  = bh - (hf ? CbArg : 0);
                    if (n < DIMV) {
                        Ch[(long long)b * (2 * SEQ * DIMV) + (long long)(hf * SEQ + s) * DIMV + n] = f2bf(val);
                    } else {
                        Ch2[(long long)b * (2 * SEQ * DIMV) + (long long)(n - DIMV) * (2 * SEQ) + hf * SEQ + s] = f2bf(val);
                    }
                }
            }
        }
    }
}

// ---------------------------------------------------------------------------
// 128x128 tile GEMM, BK=32 ring-3 depth-1 (verified rounds 0-5) — kept for
// PV, whose per-batch grid underfills the chip at 256^2 tiles. mode 0 only.
// ---------------------------------------------------------------------------
__global__ __launch_bounds__(256) void gemm_bf16_nt(
    const ushort_t* __restrict__ A, const ushort_t* __restrict__ B,
    const float* __restrict__ bias, void* __restrict__ Cout,
    int K, int lda, int ldb, int ldc, float scale,
    long long sAz, long long sBz, long long sCz)
{
    int bx = blockIdx.x, by = blockIdx.y, bz = blockIdx.z;
    {
        const unsigned Z  = gridDim.z;
        const unsigned nx = gridDim.x, ny = gridDim.y;
        if (Z > 1) {
            const unsigned nxy = nx * ny;
            const unsigned lid = ((unsigned)bz * ny + (unsigned)by) * nx + (unsigned)bx;
            unsigned r;
            if ((Z & 7u) == 0u) {
                const unsigned c  = lid & 7u;
                const unsigned rp = lid >> 3;
                bz = (int)(c + 8u * (rp / nxy));
                r  = rp % nxy;
            } else {
                bz = (int)(lid % Z);
                r  = lid / Z;
            }
            bx = (int)(r % nx);
            by = (int)(r / nx);
        } else {
            const unsigned nwg = nx * ny;
            if ((nwg & 7u) == 0u) {
                const unsigned lid = (unsigned)by * nx + (unsigned)bx;
                const unsigned nl  = (lid & 7u) * (nwg >> 3) + (lid >> 3);
                bx = (int)(nl % nx);
                by = (int)(nl / nx);
            }
        }
    }

    A += (long long)bz * sAz;
    B += (long long)bz * sBz;
    float* Cf = (float*)Cout + (long long)bz * sCz;

    __shared__ ushort_t As[3][128 * 32];
    __shared__ ushort_t Bs[3][128 * 32];

    const int t    = threadIdx.x;
    const int wave = t >> 6;
    const int lane = t & 63;
    const int quad = lane >> 4;
    const int lr   = lane & 15;
    const int wy   = wave >> 1;
    const int wx   = wave & 1;

    const int m0 = by * 128;
    const int n0 = bx * 128;

    const ushort_t* Abase = A + (long long)m0 * lda;
    const ushort_t* Bbase = B + (long long)n0 * ldb;

    auto issue = [&](int k0, int slot) {
        #pragma unroll
        for (int i = 0; i < 2; ++i) {
            const int idx = t + 256 * i;
            const int r   = idx >> 2;
            const int q   = idx & 3;
            const int c   = (q ^ ((r >> 1) & 3)) * 8;
            __builtin_amdgcn_global_load_lds(
                (const __attribute__((address_space(1))) unsigned int*)(Abase + (long long)r * lda + k0 + c),
                (__attribute__((address_space(3))) unsigned int*)&As[slot][idx * 8], 16, 0, 0);
            __builtin_amdgcn_global_load_lds(
                (const __attribute__((address_space(1))) unsigned int*)(Bbase + (long long)r * ldb + k0 + c),
                (__attribute__((address_space(3))) unsigned int*)&Bs[slot][idx * 8], 16, 0, 0);
        }
    };

    int offA[4], offB[4];
    #pragma unroll
    for (int i = 0; i < 4; ++i) {
        const int rowA = wy * 64 + i * 16 + lr;
        offA[i] = rowA * 32 + ((quad ^ ((rowA >> 1) & 3)) * 8);
        const int rowB = wx * 64 + i * 16 + lr;
        offB[i] = rowB * 32 + ((quad ^ ((rowB >> 1) & 3)) * 8);
    }

    f32x4 acc[4][4] = {};

    const int NK = K >> 5;
    issue(0, 0);
    int cur = 0, nxt = 1;
    for (int ki = 0; ki < NK; ++ki) {
        const int kn = (ki + 1 < NK) ? (ki + 1) << 5 : 0;
        issue(kn, nxt);
        asm volatile("s_waitcnt vmcnt(4)" ::: "memory");
        asm volatile("s_barrier" ::: "memory");

        const ushort_t* as = &As[cur][0];
        const ushort_t* bs = &Bs[cur][0];
        bf16x8 af[4], bfr[4];
        #pragma unroll
        for (int i = 0; i < 4; ++i) af[i]  = *(const bf16x8*)&as[offA[i]];
        #pragma unroll
        for (int j = 0; j < 4; ++j) bfr[j] = *(const bf16x8*)&bs[offB[j]];

        #pragma unroll
        for (int i = 0; i < 4; ++i)
            #pragma unroll
            for (int j = 0; j < 4; ++j)
                acc[i][j] = __builtin_amdgcn_mfma_f32_16x16x32_bf16(
                    af[i], bfr[j], acc[i][j], 0, 0, 0);

        cur = nxt;
        nxt = (nxt == 2) ? 0 : nxt + 1;
    }

    #pragma unroll
    for (int j = 0; j < 4; ++j) {
        const int n = n0 + wx * 64 + j * 16 + lr;
        const float bv = bias ? bias[n] : 0.0f;
        #pragma unroll
        for (int i = 0; i < 4; ++i) {
            #pragma unroll
            for (int r = 0; r < 4; ++r) {
                const int m = m0 + wy * 64 + i * 16 + quad * 4 + r;
                Cf[(long long)m * ldc + n] = acc[i][j][r] * scale + bv;
            }
        }
    }
}

// ---------------------------------------------------------------------------
// f32 -> bf16 conversion, 4 elems/thread, count divisible by 1024
// ---------------------------------------------------------------------------
__global__ __launch_bounds__(256) void f32_to_bf16(
    const float* __restrict__ in, ushort_t* __restrict__ out)
{
    const long long i = ((long long)blockIdx.x * 256 + threadIdx.x) * 4;
    float4 v = *reinterpret_cast<const float4*>(in + i);
    ushort4 o;
    o.x = f2bf(v.x); o.y = f2bf(v.y); o.z = f2bf(v.z); o.w = f2bf(v.w);
    *reinterpret_cast<ushort4*>(out + i) = o;
}

// ---------------------------------------------------------------------------
// Dual in-place row softmax over a [2048] f32 row (two independent 1024
// halves). Row overwritten with 2048 contiguous bf16 probs. [verified r4]
// ---------------------------------------------------------------------------
__global__ __launch_bounds__(256) void softmax2_inplace(float* __restrict__ S)
{
    float* s = S + (long long)blockIdx.x * (2 * SEQ);
    const int t  = threadIdx.x;
    const int hf = t >> 7;
    const int tt = t & 127;
    const int base = hf * SEQ + tt * 8;
    __shared__ float red[256];

    float4 v0 = *reinterpret_cast<const float4*>(&s[base]);
    float4 v1 = *reinterpret_cast<const float4*>(&s[base + 4]);
    float mx = fmaxf(fmaxf(fmaxf(v0.x, v0.y), fmaxf(v0.z, v0.w)),
                     fmaxf(fmaxf(v1.x, v1.y), fmaxf(v1.z, v1.w)));
    red[t] = mx;
    __syncthreads();
    for (int st = 64; st > 0; st >>= 1) {
        if (tt < st) red[t] = fmaxf(red[t], red[t + st]);
        __syncthreads();
    }
    mx = red[hf << 7];
    __syncthreads();

    v0.x = __expf(v0.x - mx); v0.y = __expf(v0.y - mx);
    v0.z = __expf(v0.z - mx); v0.w = __expf(v0.w - mx);
    v1.x = __expf(v1.x - mx); v1.y = __expf(v1.y - mx);
    v1.z = __expf(v1.z - mx); v1.w = __expf(v1.w - mx);
    red[t] = (v0.x + v0.y + v0.z + v0.w) + (v1.x + v1.y + v1.z + v1.w);
    __syncthreads();
    for (int st = 64; st > 0; st >>= 1) {
        if (tt < st) red[t] += red[t + st];
        __syncthreads();
    }
    const float inv = 1.0f / red[hf << 7];

    ushort4 o0, o1;
    o0.x = f2bf(v0.x * inv); o0.y = f2bf(v0.y * inv);
    o0.z = f2bf(v0.z * inv); o0.w = f2bf(v0.w * inv);
    o1.x = f2bf(v1.x * inv); o1.y = f2bf(v1.y * inv);
    o1.z = f2bf(v1.z * inv); o1.w = f2bf(v1.w * inv);
    *reinterpret_cast<ushort4*>((ushort_t*)s + base)     = o0;
    *reinterpret_cast<ushort4*>((ushort_t*)s + base + 4) = o1;
}

// ---------------------------------------------------------------------------
// h = LayerNorm(ACC + xC) * gamma + beta -> bf16. One block per row (768).
// ---------------------------------------------------------------------------
__global__ __launch_bounds__(256) void add_layernorm(
    const float* __restrict__ ACC, const float* __restrict__ xC,
    const float* __restrict__ gamma, const float* __restrict__ beta,
    ushort_t* __restrict__ H)
{
    const long long row = blockIdx.x;
    const float* a = ACC + row * DIMV;
    const float* x = xC  + row * DIMV;
    ushort_t*    h = H   + row * DIMV;
    const int t = threadIdx.x;

    __shared__ float r1[256];
    __shared__ float r2[256];

    float vals[3];
    float s = 0.f, ss = 0.f;
    #pragma unroll
    for (int i = 0; i < 3; ++i) {
        const int j = t + i * 256;
        float v = a[j] + x[j];
        vals[i] = v;
        s += v; ss += v * v;
    }
    r1[t] = s; r2[t] = ss;
    __syncthreads();
    for (int st = 128; st > 0; st >>= 1) {
        if (t < st) { r1[t] += r1[t + st]; r2[t] += r2[t + st]; }
        __syncthreads();
    }
    const float mu  = r1[0] * (1.0f / DIMV);
    const float var = r2[0] * (1.0f / DIMV) - mu * mu;
    const float inv = rsqrtf(var + LN_EPS);

    #pragma unroll
    for (int i = 0; i < 3; ++i) {
        const int j = t + i * 256;
        h[j] = f2bf((vals[i] - mu) * inv * gamma[j] + beta[j]);
    }
}

// ---------------------------------------------------------------------------
// Launch. Persistent: bf16 weights Wqb | Wkvb (=[Wk;Wv]) | Wfcb (4.72 MB).
// Lifetime-overlay layout per chunk [verified round 5, single chunk Cb=16]:
//   Region S: xCb / xABb / Sf (sequential lifetimes)
//   Qb; KbACC (Kb overlaid by ACC per sub-pass); Vtb
// Attention branch-fused per SC-batch sub-pass:
//   score (N=2048) -> dual softmax -> PV (K=2048, no RMW).
// 256^2 BK=64 ring-2 GEMM for Q/KV/score/fc; 128^2 ring-3 for PV.
// ---------------------------------------------------------------------------
extern "C" void kernel_launch(void* const* d_in, const int* in_sizes, int n_in,
                              void* d_out, int out_size, void* d_ws, size_t ws_size,
                              hipStream_t stream)
{
    const float* xA    = (const float*)d_in[0];
    const float* xB    = (const float*)d_in[1];
    const float* xC    = (const float*)d_in[2];
    const float* Wq    = (const float*)d_in[3];
    const float* bq    = (const float*)d_in[4];
    const float* Wk    = (const float*)d_in[5];
    const float* bk    = (const float*)d_in[6];
    const float* Wv    = (const float*)d_in[7];
    const float* bv    = (const float*)d_in[8];
    const float* gamma = (const float*)d_in[9];
    const float* beta  = (const float*)d_in[10];
    const float* Wfc   = (const float*)d_in[11];
    const float* bfc   = (const float*)d_in[12];
    float* out = (float*)d_out;

    const long long eW   = (long long)DIMV * DIMV;   // 589,824
    const long long perB = (long long)SEQ * DIMV;    // 786,432 elems
    const long long perP = (long long)SEQ * SEQ;     // 1,048,576 elems

    const long long wBytes = 4 * eW * 2;             // 4.72 MB

    auto needBytes = [&](long long cb, long long sc) {
        const long long s = 8 * perP * sc;           // Sf f32 bytes
        const long long x = 4 * perB * cb;           // xABb bf16 bytes
        return (s > x ? s : x) + 10 * perB * cb;     // + Qb + KbACC + Vtb
    };

    int CbFit = 1;
    for (int c = BATCH; c >= 1; --c) {
        const long long sc = c < 8 ? c : 8;
        if (wBytes + needBytes(c, sc) <= (long long)ws_size) { CbFit = c; break; }
    }
    const int nChunks = (BATCH + CbFit - 1) / CbFit;
    const int CbStd   = (BATCH + nChunks - 1) / nChunks;

    char* cur = (char*)d_ws;
    ushort_t* Wqb  = (ushort_t*)cur; cur += eW * 2;
    ushort_t* Wkvb = (ushort_t*)cur; cur += 2 * eW * 2;    // [Wk; Wv] 1536x768
    ushort_t* Wfcb = (ushort_t*)cur; cur += eW * 2;
    char* chunkBase = cur;

    const float scale = 0.03608439182435161f;  // 1/sqrt(768)

    f32_to_bf16<<<(int)(eW / 1024), 256, 0, stream>>>(Wq,  Wqb);
    f32_to_bf16<<<(int)(eW / 1024), 256, 0, stream>>>(Wk,  Wkvb);
    f32_to_bf16<<<(int)(eW / 1024), 256, 0, stream>>>(Wv,  Wkvb + eW);
    f32_to_bf16<<<(int)(eW / 1024), 256, 0, stream>>>(Wfc, Wfcb);

    for (int b0 = 0; b0 < BATCH; b0 += CbStd) {
        const int Cb = (b0 + CbStd <= BATCH) ? CbStd : (BATCH - b0);
        const long long off = (long long)b0 * perB;

        int SC = Cb;
        while (SC > 1 && wBytes + needBytes(Cb, SC) > (long long)ws_size) --SC;

        const long long Sbytes =
            (8 * perP * (long long)SC > 4 * perB * (long long)Cb)
                ? 8 * perP * (long long)SC : 4 * perB * (long long)Cb;

        char* p = chunkBase;
        ushort_t* xCb  = (ushort_t*)p;                 // overlay 1 in region S
        ushort_t* xABb = (ushort_t*)p;                 // overlay 2 in region S
        float*    Sf   = (float*)p;    p += Sbytes;    // overlay 3 in region S
        ushort_t* Qb   = (ushort_t*)p; p += 2 * perB * Cb;
        ushort_t* Kb   = (ushort_t*)p;
        float*    ACC  = (float*)p;    p += 4 * perB * Cb;   // ACC overlays Kb
        ushort_t* Vtb  = (ushort_t*)p; p += 4 * perB * Cb;

        dim3 gq  (DIMV / 256, Cb * (SEQ / 256), 1);           // (3, 64)
        dim3 gkv (2 * DIMV / 256, 2 * Cb * (SEQ / 256), 1);   // (6, 128)
        const int gcv = (int)((long long)Cb * perB / 1024);

        // 1) projections: Q from xC; fused K|V GEMM from stacked xA|xB
        f32_to_bf16<<<gcv, 256, 0, stream>>>(xC + off, xCb);
        gemm_bf16_nt_256<<<gq, 512, 0, stream>>>(xCb, Wqb, bq, nullptr, Qb, nullptr,
            DIMV, DIMV, DIMV, DIMV, 1.f, 1, 0, 0, 0, 0);
        f32_to_bf16<<<gcv, 256, 0, stream>>>(xA + off, xABb);
        f32_to_bf16<<<gcv, 256, 0, stream>>>(xB + off, xABb + (long long)Cb * perB);
        gemm_bf16_nt_256<<<gkv, 512, 0, stream>>>(xABb, Wkvb, bk, bv, Kb, Vtb,
            DIMV, DIMV, DIMV, DIMV, 1.f, 4, 0, 0, 0, Cb);

        // 2) branch-fused attention, SC batches per sub-pass
        for (int s0 = 0; s0 < Cb; s0 += SC) {
            const int sc = (s0 + SC <= Cb) ? SC : (Cb - s0);
            dim3 gsc(2 * SEQ / 256, SEQ / 256, sc);           // (8, 4, sc)
            dim3 gpv(DIMV / 128, SEQ / 128, sc);              // 128^2 kernel

            gemm_bf16_nt_256<<<gsc, 512, 0, stream>>>(
                Qb + (long long)s0 * perB, Kb + (long long)s0 * 2 * perB,
                nullptr, nullptr, Sf, nullptr,
                DIMV, DIMV, DIMV, 2 * SEQ, scale, 0, perB, 2 * perB, 2 * perP, 0);

            softmax2_inplace<<<sc * SEQ, 256, 0, stream>>>(Sf);

            gemm_bf16_nt<<<gpv, 256, 0, stream>>>(
                (const ushort_t*)Sf, Vtb + (long long)s0 * 2 * perB,
                nullptr, ACC + (long long)s0 * perB,
                2 * SEQ, 4 * SEQ, 2 * SEQ, DIMV, 1.f, 4 * perP, 2 * perB, perB);
        }

        // 3) h = LN(ACC + xC) -> bf16, into Qb (Q is dead now)
        add_layernorm<<<Cb * SEQ, 256, 0, stream>>>(ACC, xC + off, gamma, beta, Qb);

        // 4) out = h @ Wfc^T + bfc (f32 out)
        gemm_bf16_nt_256<<<gq, 512, 0, stream>>>(Qb, Wfcb, bfc, nullptr, out + off, nullptr,
            DIMV, DIMV, DIMV, DIMV, 1.f, 0, 0, 0, 0, 0);
    }
}

// Round 9
// 638.835 us; speedup vs baseline: 1.0133x; 1.0133x over previous
//
#include <hip/hip_runtime.h>

#define DIMV 768
#define BATCH 16
#define SEQ 1024
#define LN_EPS 1e-5f

typedef __attribute__((ext_vector_type(8))) short bf16x8;   // 8 bf16 = 4 VGPRs
typedef __attribute__((ext_vector_type(4))) float f32x4;
typedef unsigned short ushort_t;

__device__ __forceinline__ unsigned short f2bf(float f) {
    unsigned u = __float_as_uint(f);
    u = (u + 0x7FFFu + ((u >> 16) & 1u)) >> 16;
    return (unsigned short)u;
}

// ---------------------------------------------------------------------------
// Verified building blocks (rounds 0-8):
//  - LDS chunk swizzle on global SOURCE + frag-read XOR (conflicts -> 0).
//  - XCD swizzles: Z>1 -> XCD == batch (mod 8); Z==1 -> chunked y-range.
//  - Branch-fused attention; lifetime overlays -> single chunk Cb=16.
// 2-phase family EXHAUSTED (all pre-committed A/B outcomes, ~460-480 TF):
//  depth-2 @128^2 (r4), tile 256^2 (r6 +6.6%), depth-2 iso-occ (r7 null),
//  BK=64 ring-2 (r8 null). Remaining measured lever: 8-phase fine
//  interleave with counted vmcnt (T3+T4) + setprio (T5).
// ---------------------------------------------------------------------------

// ---------------------------------------------------------------------------
// 256x256 tile GEMM, 8-PHASE schedule, BK=64 (two 32-wide k-halves):
// LDS [2 buf][2 khalf][256x32] bf16 per matrix (128 KB). Half-tile = 16 KB
// = 2 global_load_lds/thread, contiguous LDS dest, 2-bit bank swizzle
// q^((r>>1)&3) applied on the GLOBAL source (verified: conflicts -> 0).
//
// Phase p (0..3) of K-tile j: kh=p>>1, sub=p&1.
//   ds_read: af[4] rows i in [4sub,4sub+4) from A[j&1][kh]
//            (+ bfr[4] from B[j&1][kh] when sub==0; reused when sub==1)
//   stage ONE half-tile: p0 -> A-kh1(j+1), p1 -> B-kh1(j+1),
//                        p2 -> A-kh0(j+2), p3 -> B-kh0(j+2)
//   16 MFMA (setprio 1/0) ; s_waitcnt lgkmcnt(0) ; [p==3: vmcnt(4)] ; s_barrier
//
// Safety (phase-global order; reads DRAIN via lgkmcnt(0) before each barrier):
//  - write-after-read: each stage overwrites a region whose last read is >=1
//    phase earlier (p2 stages A-kh0(j+2) over A-kh0(j), last read p1; p0
//    stages A-kh1(j+1) over A-kh1(j-1), last read = previous phase; etc.)
//  - readiness: prologue = 6 half-tiles; vmcnt(4) at K-tile boundaries only
//    (2 newest half-tiles may fly; oldest-first => K-tile j fully landed).
//    Never drains to 0 in the loop (T4).
//  - tail: re-stage the identical resident region (same src/dst -> same
//    bytes; its reads are provably complete) to keep vmcnt counts uniform.
// Requires NK >= 2 (all callers use K=768 -> NK=12).
// mode: 0 = f32 out; 1 = bf16 out; 4 = fused KV epilogue (branch-stacked).
// ---------------------------------------------------------------------------
__global__ __launch_bounds__(512, 2) void gemm_bf16_nt_256(
    const ushort_t* __restrict__ A, const ushort_t* __restrict__ B,
    const float* __restrict__ bias, const float* __restrict__ bias2,
    void* __restrict__ Cout, void* __restrict__ Cout2,
    int K, int lda, int ldb, int ldc, float scale, int mode,
    long long sAz, long long sBz, long long sCz, int CbArg)
{
    int bx = blockIdx.x, by = blockIdx.y, bz = blockIdx.z;
    {
        const unsigned Z  = gridDim.z;
        const unsigned nx = gridDim.x, ny = gridDim.y;
        if (Z > 1) {
            const unsigned nxy = nx * ny;
            const unsigned lid = ((unsigned)bz * ny + (unsigned)by) * nx + (unsigned)bx;
            unsigned r;
            if ((Z & 7u) == 0u) {
                const unsigned c  = lid & 7u;
                const unsigned rp = lid >> 3;
                bz = (int)(c + 8u * (rp / nxy));
                r  = rp % nxy;
            } else {
                bz = (int)(lid % Z);
                r  = lid / Z;
            }
            bx = (int)(r % nx);
            by = (int)(r / nx);
        } else {
            const unsigned nwg = nx * ny;
            if ((nwg & 7u) == 0u) {
                const unsigned lid = (unsigned)by * nx + (unsigned)bx;
                const unsigned nl  = (lid & 7u) * (nwg >> 3) + (lid >> 3);
                bx = (int)(nl % nx);
                by = (int)(nl / nx);
            }
        }
    }

    A += (long long)bz * sAz;
    B += (long long)bz * sBz;
    float*    Cf  = (float*)Cout    + ((mode == 0) ? (long long)bz * sCz : 0);
    ushort_t* Ch  = (ushort_t*)Cout + ((mode == 1) ? (long long)bz * sCz : 0);
    ushort_t* Ch2 = (ushort_t*)Cout2;

    __shared__ ushort_t As[2][2][256 * 32];   // [buf][khalf] 16 KB each
    __shared__ ushort_t Bs[2][2][256 * 32];   // 128 KB total

    const int t    = threadIdx.x;       // 0..511
    const int wave = t >> 6;            // 0..7
    const int lane = t & 63;
    const int quad = lane >> 4;         // 0..3
    const int lr   = lane & 15;         // 0..15
    const int wy   = wave >> 2;         // 0/1: m-half (128 rows)
    const int wx   = wave & 3;          // 0..3: n-quarter (64 cols)

    const int m0 = by * 256;
    const int n0 = bx * 256;

    const ushort_t* Abase = A + (long long)m0 * lda;
    const ushort_t* Bbase = B + (long long)n0 * ldb;

    // stage one half-tile (16 KB): 256 rows x 4 swizzled 16B chunks
    auto stageA = [&](int jH, int kh) {
        const int k0 = jH * 64 + kh * 32;
        #pragma unroll
        for (int i = 0; i < 2; ++i) {
            const int idx = t + 512 * i;          // 0..1023
            const int r   = idx >> 2;
            const int q   = idx & 3;
            const int c   = (q ^ ((r >> 1) & 3)) * 8;
            __builtin_amdgcn_global_load_lds(
                (const __attribute__((address_space(1))) unsigned int*)(Abase + (long long)r * lda + k0 + c),
                (__attribute__((address_space(3))) unsigned int*)&As[jH & 1][kh][idx * 8], 16, 0, 0);
        }
    };
    auto stageB = [&](int jH, int kh) {
        const int k0 = jH * 64 + kh * 32;
        #pragma unroll
        for (int i = 0; i < 2; ++i) {
            const int idx = t + 512 * i;
            const int r   = idx >> 2;
            const int q   = idx & 3;
            const int c   = (q ^ ((r >> 1) & 3)) * 8;
            __builtin_amdgcn_global_load_lds(
                (const __attribute__((address_space(1))) unsigned int*)(Bbase + (long long)r * ldb + k0 + c),
                (__attribute__((address_space(3))) unsigned int*)&Bs[jH & 1][kh][idx * 8], 16, 0, 0);
        }
    };

    // Region-relative frag offsets (64 B rows inside a khalf region)
    int offA[8], offB[4];
    #pragma unroll
    for (int i = 0; i < 8; ++i) {
        const int rA = wy * 128 + i * 16 + lr;
        offA[i] = rA * 32 + ((quad ^ ((rA >> 1) & 3)) * 8);
    }
    #pragma unroll
    for (int j4 = 0; j4 < 4; ++j4) {
        const int rB = wx * 64 + j4 * 16 + lr;
        offB[j4] = rB * 32 + ((quad ^ ((rB >> 1) & 3)) * 8);
    }

    f32x4 acc[8][4] = {};

    const int NK = K >> 6;   // K=768 -> 12 (all callers)

    // prologue: half-tiles H=0..5 = {A0h0,B0h0,A0h1,B0h1,A1h0,B1h0}
    stageA(0, 0); stageB(0, 0); stageA(0, 1); stageB(0, 1);
    stageA(1, 0); stageB(1, 0);
    asm volatile("s_waitcnt vmcnt(4)" ::: "memory");   // K-tile 0 landed
    asm volatile("s_barrier" ::: "memory");

    for (int j = 0; j < NK; ++j) {
        const ushort_t* a0 = &As[j & 1][0][0];
        const ushort_t* a1 = &As[j & 1][1][0];
        const ushort_t* b0 = &Bs[j & 1][0][0];
        const ushort_t* b1 = &Bs[j & 1][1][0];
        bf16x8 bfr[4];

        // ---- phase 0: kh=0, i in [0,4) ----
        {
            bf16x8 af[4];
            #pragma unroll
            for (int q4 = 0; q4 < 4; ++q4) bfr[q4] = *(const bf16x8*)&b0[offB[q4]];
            #pragma unroll
            for (int i2 = 0; i2 < 4; ++i2) af[i2] = *(const bf16x8*)&a0[offA[i2]];
            stageA((j < NK - 1) ? j + 1 : j - 1, 1);
            __builtin_amdgcn_s_setprio(1);
            #pragma unroll
            for (int i2 = 0; i2 < 4; ++i2)
                #pragma unroll
                for (int q4 = 0; q4 < 4; ++q4)
                    acc[i2][q4] = __builtin_amdgcn_mfma_f32_16x16x32_bf16(
                        af[i2], bfr[q4], acc[i2][q4], 0, 0, 0);
            __builtin_amdgcn_s_setprio(0);
            asm volatile("s_waitcnt lgkmcnt(0)" ::: "memory");
            asm volatile("s_barrier" ::: "memory");
        }
        // ---- phase 1: kh=0, i in [4,8) ----
        {
            bf16x8 af[4];
            #pragma unroll
            for (int i2 = 0; i2 < 4; ++i2) af[i2] = *(const bf16x8*)&a0[offA[4 + i2]];
            stageB((j < NK - 1) ? j + 1 : j - 1, 1);
            __builtin_amdgcn_s_setprio(1);
            #pragma unroll
            for (int i2 = 0; i2 < 4; ++i2)
                #pragma unroll
                for (int q4 = 0; q4 < 4; ++q4)
                    acc[4 + i2][q4] = __builtin_amdgcn_mfma_f32_16x16x32_bf16(
                        af[i2], bfr[q4], acc[4 + i2][q4], 0, 0, 0);
            __builtin_amdgcn_s_setprio(0);
            asm volatile("s_waitcnt lgkmcnt(0)" ::: "memory");
            asm volatile("s_barrier" ::: "memory");
        }
        // ---- phase 2: kh=1, i in [0,4) ----
        {
            bf16x8 af[4];
            #pragma unroll
            for (int q4 = 0; q4 < 4; ++q4) bfr[q4] = *(const bf16x8*)&b1[offB[q4]];
            #pragma unroll
            for (int i2 = 0; i2 < 4; ++i2) af[i2] = *(const bf16x8*)&a1[offA[i2]];
            stageA((j < NK - 2) ? j + 2 : j, 0);
            __builtin_amdgcn_s_setprio(1);
            #pragma unroll
            for (int i2 = 0; i2 < 4; ++i2)
                #pragma unroll
                for (int q4 = 0; q4 < 4; ++q4)
                    acc[i2][q4] = __builtin_amdgcn_mfma_f32_16x16x32_bf16(
                        af[i2], bfr[q4], acc[i2][q4], 0, 0, 0);
            __builtin_amdgcn_s_setprio(0);
            asm volatile("s_waitcnt lgkmcnt(0)" ::: "memory");
            asm volatile("s_barrier" ::: "memory");
        }
        // ---- phase 3: kh=1, i in [4,8); K-tile boundary vmcnt ----
        {
            bf16x8 af[4];
            #pragma unroll
            for (int i2 = 0; i2 < 4; ++i2) af[i2] = *(const bf16x8*)&a1[offA[4 + i2]];
            stageB((j < NK - 2) ? j + 2 : j, 0);
            __builtin_amdgcn_s_setprio(1);
            #pragma unroll
            for (int i2 = 0; i2 < 4; ++i2)
                #pragma unroll
                for (int q4 = 0; q4 < 4; ++q4)
                    acc[4 + i2][q4] = __builtin_amdgcn_mfma_f32_16x16x32_bf16(
                        af[i2], bfr[q4], acc[4 + i2][q4], 0, 0, 0);
            __builtin_amdgcn_s_setprio(0);
            asm volatile("s_waitcnt lgkmcnt(0)" ::: "memory");
            asm volatile("s_waitcnt vmcnt(4)" ::: "memory");   // next K-tile landed
            asm volatile("s_barrier" ::: "memory");
        }
    }

    // epilogue: D row(m) = quad*4 + reg, col(n) = lane&15  [m89-verified]
    #pragma unroll
    for (int j = 0; j < 4; ++j) {
        const int n = n0 + wx * 64 + j * 16 + lr;
        float bv;
        if (mode == 4) bv = (n < DIMV) ? bias[n] : bias2[n - DIMV];
        else           bv = bias ? bias[n] : 0.0f;
        #pragma unroll
        for (int i = 0; i < 8; ++i) {
            #pragma unroll
            for (int r = 0; r < 4; ++r) {
                const int m = m0 + wy * 128 + i * 16 + quad * 4 + r;
                const float val = acc[i][j][r] * scale + bv;
                if (mode == 0) {
                    Cf[(long long)m * ldc + n] = val;
                } else if (mode == 1) {
                    Ch[(long long)m * ldc + n] = f2bf(val);
                } else {                      // mode 4: fused KV, branch-stacked
                    const int bh = m >> 10, s = m & 1023;
                    const int hf = (bh >= CbArg) ? 1 : 0;
                    const int b  = bh - (hf ? CbArg : 0);
                    if (n < DIMV) {
                        Ch[(long long)b * (2 * SEQ * DIMV) + (long long)(hf * SEQ + s) * DIMV + n] = f2bf(val);
                    } else {
                        Ch2[(long long)b * (2 * SEQ * DIMV) + (long long)(n - DIMV) * (2 * SEQ) + hf * SEQ + s] = f2bf(val);
                    }
                }
            }
        }
    }
}

// ---------------------------------------------------------------------------
// 128x128 tile GEMM, BK=32 ring-3 depth-1 (verified rounds 0-5) — kept for
// PV, whose per-batch grid underfills the chip at 256^2 tiles. mode 0 only.
// ---------------------------------------------------------------------------
__global__ __launch_bounds__(256) void gemm_bf16_nt(
    const ushort_t* __restrict__ A, const ushort_t* __restrict__ B,
    const float* __restrict__ bias, void* __restrict__ Cout,
    int K, int lda, int ldb, int ldc, float scale,
    long long sAz, long long sBz, long long sCz)
{
    int bx = blockIdx.x, by = blockIdx.y, bz = blockIdx.z;
    {
        const unsigned Z  = gridDim.z;
        const unsigned nx = gridDim.x, ny = gridDim.y;
        if (Z > 1) {
            const unsigned nxy = nx * ny;
            const unsigned lid = ((unsigned)bz * ny + (unsigned)by) * nx + (unsigned)bx;
            unsigned r;
            if ((Z & 7u) == 0u) {
                const unsigned c  = lid & 7u;
                const unsigned rp = lid >> 3;
                bz = (int)(c + 8u * (rp / nxy));
                r  = rp % nxy;
            } else {
                bz = (int)(lid % Z);
                r  = lid / Z;
            }
            bx = (int)(r % nx);
            by = (int)(r / nx);
        } else {
            const unsigned nwg = nx * ny;
            if ((nwg & 7u) == 0u) {
                const unsigned lid = (unsigned)by * nx + (unsigned)bx;
                const unsigned nl  = (lid & 7u) * (nwg >> 3) + (lid >> 3);
                bx = (int)(nl % nx);
                by = (int)(nl / nx);
            }
        }
    }

    A += (long long)bz * sAz;
    B += (long long)bz * sBz;
    float* Cf = (float*)Cout + (long long)bz * sCz;

    __shared__ ushort_t As[3][128 * 32];
    __shared__ ushort_t Bs[3][128 * 32];

    const int t    = threadIdx.x;
    const int wave = t >> 6;
    const int lane = t & 63;
    const int quad = lane >> 4;
    const int lr   = lane & 15;
    const int wy   = wave >> 1;
    const int wx   = wave & 1;

    const int m0 = by * 128;
    const int n0 = bx * 128;

    const ushort_t* Abase = A + (long long)m0 * lda;
    const ushort_t* Bbase = B + (long long)n0 * ldb;

    auto issue = [&](int k0, int slot) {
        #pragma unroll
        for (int i = 0; i < 2; ++i) {
            const int idx = t + 256 * i;
            const int r   = idx >> 2;
            const int q   = idx & 3;
            const int c   = (q ^ ((r >> 1) & 3)) * 8;
            __builtin_amdgcn_global_load_lds(
                (const __attribute__((address_space(1))) unsigned int*)(Abase + (long long)r * lda + k0 + c),
                (__attribute__((address_space(3))) unsigned int*)&As[slot][idx * 8], 16, 0, 0);
            __builtin_amdgcn_global_load_lds(
                (const __attribute__((address_space(1))) unsigned int*)(Bbase + (long long)r * ldb + k0 + c),
                (__attribute__((address_space(3))) unsigned int*)&Bs[slot][idx * 8], 16, 0, 0);
        }
    };

    int offA[4], offB[4];
    #pragma unroll
    for (int i = 0; i < 4; ++i) {
        const int rowA = wy * 64 + i * 16 + lr;
        offA[i] = rowA * 32 + ((quad ^ ((rowA >> 1) & 3)) * 8);
        const int rowB = wx * 64 + i * 16 + lr;
        offB[i] = rowB * 32 + ((quad ^ ((rowB >> 1) & 3)) * 8);
    }

    f32x4 acc[4][4] = {};

    const int NK = K >> 5;
    issue(0, 0);
    int cur = 0, nxt = 1;
    for (int ki = 0; ki < NK; ++ki) {
        const int kn = (ki + 1 < NK) ? (ki + 1) << 5 : 0;
        issue(kn, nxt);
        asm volatile("s_waitcnt vmcnt(4)" ::: "memory");
        asm volatile("s_barrier" ::: "memory");

        const ushort_t* as = &As[cur][0];
        const ushort_t* bs = &Bs[cur][0];
        bf16x8 af[4], bfr[4];
        #pragma unroll
        for (int i = 0; i < 4; ++i) af[i]  = *(const bf16x8*)&as[offA[i]];
        #pragma unroll
        for (int j = 0; j < 4; ++j) bfr[j] = *(const bf16x8*)&bs[offB[j]];

        #pragma unroll
        for (int i = 0; i < 4; ++i)
            #pragma unroll
            for (int j = 0; j < 4; ++j)
                acc[i][j] = __builtin_amdgcn_mfma_f32_16x16x32_bf16(
                    af[i], bfr[j], acc[i][j], 0, 0, 0);

        cur = nxt;
        nxt = (nxt == 2) ? 0 : nxt + 1;
    }

    #pragma unroll
    for (int j = 0; j < 4; ++j) {
        const int n = n0 + wx * 64 + j * 16 + lr;
        const float bv = bias ? bias[n] : 0.0f;
        #pragma unroll
        for (int i = 0; i < 4; ++i) {
            #pragma unroll
            for (int r = 0; r < 4; ++r) {
                const int m = m0 + wy * 64 + i * 16 + quad * 4 + r;
                Cf[(long long)m * ldc + n] = acc[i][j][r] * scale + bv;
            }
        }
    }
}

// ---------------------------------------------------------------------------
// f32 -> bf16 conversion, 4 elems/thread, count divisible by 1024
// ---------------------------------------------------------------------------
__global__ __launch_bounds__(256) void f32_to_bf16(
    const float* __restrict__ in, ushort_t* __restrict__ out)
{
    const long long i = ((long long)blockIdx.x * 256 + threadIdx.x) * 4;
    float4 v = *reinterpret_cast<const float4*>(in + i);
    ushort4 o;
    o.x = f2bf(v.x); o.y = f2bf(v.y); o.z = f2bf(v.z); o.w = f2bf(v.w);
    *reinterpret_cast<ushort4*>(out + i) = o;
}

// ---------------------------------------------------------------------------
// Dual in-place row softmax over a [2048] f32 row (two independent 1024
// halves). Row overwritten with 2048 contiguous bf16 probs. [verified r4]
// ---------------------------------------------------------------------------
__global__ __launch_bounds__(256) void softmax2_inplace(float* __restrict__ S)
{
    float* s = S + (long long)blockIdx.x * (2 * SEQ);
    const int t  = threadIdx.x;
    const int hf = t >> 7;
    const int tt = t & 127;
    const int base = hf * SEQ + tt * 8;
    __shared__ float red[256];

    float4 v0 = *reinterpret_cast<const float4*>(&s[base]);
    float4 v1 = *reinterpret_cast<const float4*>(&s[base + 4]);
    float mx = fmaxf(fmaxf(fmaxf(v0.x, v0.y), fmaxf(v0.z, v0.w)),
                     fmaxf(fmaxf(v1.x, v1.y), fmaxf(v1.z, v1.w)));
    red[t] = mx;
    __syncthreads();
    for (int st = 64; st > 0; st >>= 1) {
        if (tt < st) red[t] = fmaxf(red[t], red[t + st]);
        __syncthreads();
    }
    mx = red[hf << 7];
    __syncthreads();

    v0.x = __expf(v0.x - mx); v0.y = __expf(v0.y - mx);
    v0.z = __expf(v0.z - mx); v0.w = __expf(v0.w - mx);
    v1.x = __expf(v1.x - mx); v1.y = __expf(v1.y - mx);
    v1.z = __expf(v1.z - mx); v1.w = __expf(v1.w - mx);
    red[t] = (v0.x + v0.y + v0.z + v0.w) + (v1.x + v1.y + v1.z + v1.w);
    __syncthreads();
    for (int st = 64; st > 0; st >>= 1) {
        if (tt < st) red[t] += red[t + st];
        __syncthreads();
    }
    const float inv = 1.0f / red[hf << 7];

    ushort4 o0, o1;
    o0.x = f2bf(v0.x * inv); o0.y = f2bf(v0.y * inv);
    o0.z = f2bf(v0.z * inv); o0.w = f2bf(v0.w * inv);
    o1.x = f2bf(v1.x * inv); o1.y = f2bf(v1.y * inv);
    o1.z = f2bf(v1.z * inv); o1.w = f2bf(v1.w * inv);
    *reinterpret_cast<ushort4*>((ushort_t*)s + base)     = o0;
    *reinterpret_cast<ushort4*>((ushort_t*)s + base + 4) = o1;
}

// ---------------------------------------------------------------------------
// h = LayerNorm(ACC + xC) * gamma + beta -> bf16. One block per row (768).
// ---------------------------------------------------------------------------
__global__ __launch_bounds__(256) void add_layernorm(
    const float* __restrict__ ACC, const float* __restrict__ xC,
    const float* __restrict__ gamma, const float* __restrict__ beta,
    ushort_t* __restrict__ H)
{
    const long long row = blockIdx.x;
    const float* a = ACC + row * DIMV;
    const float* x = xC  + row * DIMV;
    ushort_t*    h = H   + row * DIMV;
    const int t = threadIdx.x;

    __shared__ float r1[256];
    __shared__ float r2[256];

    float vals[3];
    float s = 0.f, ss = 0.f;
    #pragma unroll
    for (int i = 0; i < 3; ++i) {
        const int j = t + i * 256;
        float v = a[j] + x[j];
        vals[i] = v;
        s += v; ss += v * v;
    }
    r1[t] = s; r2[t] = ss;
    __syncthreads();
    for (int st = 128; st > 0; st >>= 1) {
        if (t < st) { r1[t] += r1[t + st]; r2[t] += r2[t + st]; }
        __syncthreads();
    }
    const float mu  = r1[0] * (1.0f / DIMV);
    const float var = r2[0] * (1.0f / DIMV) - mu * mu;
    const float inv = rsqrtf(var + LN_EPS);

    #pragma unroll
    for (int i = 0; i < 3; ++i) {
        const int j = t + i * 256;
        h[j] = f2bf((vals[i] - mu) * inv * gamma[j] + beta[j]);
    }
}

// ---------------------------------------------------------------------------
// Launch. Persistent: bf16 weights Wqb | Wkvb (=[Wk;Wv]) | Wfcb (4.72 MB).
// Lifetime-overlay layout per chunk [verified round 5, single chunk Cb=16]:
//   Region S: xCb / xABb / Sf (sequential lifetimes)
//   Qb; KbACC (Kb overlaid by ACC per sub-pass); Vtb
// Attention branch-fused per SC-batch sub-pass:
//   score (N=2048) -> dual softmax -> PV (K=2048, no RMW).
// 256^2 8-phase GEMM for Q/KV/score/fc; 128^2 ring-3 for PV.
// ---------------------------------------------------------------------------
extern "C" void kernel_launch(void* const* d_in, const int* in_sizes, int n_in,
                              void* d_out, int out_size, void* d_ws, size_t ws_size,
                              hipStream_t stream)
{
    const float* xA    = (const float*)d_in[0];
    const float* xB    = (const float*)d_in[1];
    const float* xC    = (const float*)d_in[2];
    const float* Wq    = (const float*)d_in[3];
    const float* bq    = (const float*)d_in[4];
    const float* Wk    = (const float*)d_in[5];
    const float* bk    = (const float*)d_in[6];
    const float* Wv    = (const float*)d_in[7];
    const float* bv    = (const float*)d_in[8];
    const float* gamma = (const float*)d_in[9];
    const float* beta  = (const float*)d_in[10];
    const float* Wfc   = (const float*)d_in[11];
    const float* bfc   = (const float*)d_in[12];
    float* out = (float*)d_out;

    const long long eW   = (long long)DIMV * DIMV;   // 589,824
    const long long perB = (long long)SEQ * DIMV;    // 786,432 elems
    const long long perP = (long long)SEQ * SEQ;     // 1,048,576 elems

    const long long wBytes = 4 * eW * 2;             // 4.72 MB

    auto needBytes = [&](long long cb, long long sc) {
        const long long s = 8 * perP * sc;           // Sf f32 bytes
        const long long x = 4 * perB * cb;           // xABb bf16 bytes
        return (s > x ? s : x) + 10 * perB * cb;     // + Qb + KbACC + Vtb
    };

    int CbFit = 1;
    for (int c = BATCH; c >= 1; --c) {
        const long long sc = c < 8 ? c : 8;
        if (wBytes + needBytes(c, sc) <= (long long)ws_size) { CbFit = c; break; }
    }
    const int nChunks = (BATCH + CbFit - 1) / CbFit;
    const int CbStd   = (BATCH + nChunks - 1) / nChunks;

    char* cur = (char*)d_ws;
    ushort_t* Wqb  = (ushort_t*)cur; cur += eW * 2;
    ushort_t* Wkvb = (ushort_t*)cur; cur += 2 * eW * 2;    // [Wk; Wv] 1536x768
    ushort_t* Wfcb = (ushort_t*)cur; cur += eW * 2;
    char* chunkBase = cur;

    const float scale = 0.03608439182435161f;  // 1/sqrt(768)

    f32_to_bf16<<<(int)(eW / 1024), 256, 0, stream>>>(Wq,  Wqb);
    f32_to_bf16<<<(int)(eW / 1024), 256, 0, stream>>>(Wk,  Wkvb);
    f32_to_bf16<<<(int)(eW / 1024), 256, 0, stream>>>(Wv,  Wkvb + eW);
    f32_to_bf16<<<(int)(eW / 1024), 256, 0, stream>>>(Wfc, Wfcb);

    for (int b0 = 0; b0 < BATCH; b0 += CbStd) {
        const int Cb = (b0 + CbStd <= BATCH) ? CbStd : (BATCH - b0);
        const long long off = (long long)b0 * perB;

        int SC = Cb;
        while (SC > 1 && wBytes + needBytes(Cb, SC) > (long long)ws_size) --SC;

        const long long Sbytes =
            (8 * perP * (long long)SC > 4 * perB * (long long)Cb)
                ? 8 * perP * (long long)SC : 4 * perB * (long long)Cb;

        char* p = chunkBase;
        ushort_t* xCb  = (ushort_t*)p;                 // overlay 1 in region S
        ushort_t* xABb = (ushort_t*)p;                 // overlay 2 in region S
        float*    Sf   = (float*)p;    p += Sbytes;    // overlay 3 in region S
        ushort_t* Qb   = (ushort_t*)p; p += 2 * perB * Cb;
        ushort_t* Kb   = (ushort_t*)p;
        float*    ACC  = (float*)p;    p += 4 * perB * Cb;   // ACC overlays Kb
        ushort_t* Vtb  = (ushort_t*)p; p += 4 * perB * Cb;

        dim3 gq  (DIMV / 256, Cb * (SEQ / 256), 1);           // (3, 64)
        dim3 gkv (2 * DIMV / 256, 2 * Cb * (SEQ / 256), 1);   // (6, 128)
        const int gcv = (int)((long long)Cb * perB / 1024);

        // 1) projections: Q from xC; fused K|V GEMM from stacked xA|xB
        f32_to_bf16<<<gcv, 256, 0, stream>>>(xC + off, xCb);
        gemm_bf16_nt_256<<<gq, 512, 0, stream>>>(xCb, Wqb, bq, nullptr, Qb, nullptr,
            DIMV, DIMV, DIMV, DIMV, 1.f, 1, 0, 0, 0, 0);
        f32_to_bf16<<<gcv, 256, 0, stream>>>(xA + off, xABb);
        f32_to_bf16<<<gcv, 256, 0, stream>>>(xB + off, xABb + (long long)Cb * perB);
        gemm_bf16_nt_256<<<gkv, 512, 0, stream>>>(xABb, Wkvb, bk, bv, Kb, Vtb,
            DIMV, DIMV, DIMV, DIMV, 1.f, 4, 0, 0, 0, Cb);

        // 2) branch-fused attention, SC batches per sub-pass
        for (int s0 = 0; s0 < Cb; s0 += SC) {
            const int sc = (s0 + SC <= Cb) ? SC : (Cb - s0);
            dim3 gsc(2 * SEQ / 256, SEQ / 256, sc);           // (8, 4, sc)
            dim3 gpv(DIMV / 128, SEQ / 128, sc);              // 128^2 kernel

            gemm_bf16_nt_256<<<gsc, 512, 0, stream>>>(
                Qb + (long long)s0 * perB, Kb + (long long)s0 * 2 * perB,
                nullptr, nullptr, Sf, nullptr,
                DIMV, DIMV, DIMV, 2 * SEQ, scale, 0, perB, 2 * perB, 2 * perP, 0);

            softmax2_inplace<<<sc * SEQ, 256, 0, stream>>>(Sf);

            gemm_bf16_nt<<<gpv, 256, 0, stream>>>(
                (const ushort_t*)Sf, Vtb + (long long)s0 * 2 * perB,
                nullptr, ACC + (long long)s0 * perB,
                2 * SEQ, 4 * SEQ, 2 * SEQ, DIMV, 1.f, 4 * perP, 2 * perB, perB);
        }

        // 3) h = LN(ACC + xC) -> bf16, into Qb (Q is dead now)
        add_layernorm<<<Cb * SEQ, 256, 0, stream>>>(ACC, xC + off, gamma, beta, Qb);

        // 4) out = h @ Wfc^T + bfc (f32 out)
        gemm_bf16_nt_256<<<gq, 512, 0, stream>>>(Qb, Wfcb, bfc, nullptr, out + off, nullptr,
            DIMV, DIMV, DIMV, DIMV, 1.f, 0, 0, 0, 0, 0);
    }
}